// Round 14
// baseline (593.700 us; speedup 1.0000x reference)
//
#include <hip/hip_runtime.h>
#include <math.h>

#define N_VOX 200000
#define CCH   128
#define KOFF  27

typedef __attribute__((ext_vector_type(8))) short bf16x8;
typedef __attribute__((ext_vector_type(4))) float f32x4;

__device__ __forceinline__ float silu_f(float x) {
    return x / (1.0f + expf(-x));
}
__device__ __forceinline__ unsigned short f2bf(float x) {
    unsigned int u = __float_as_uint(x);
    u = (u + 0x7FFFu + ((u >> 16) & 1u)) >> 16;
    return (unsigned short)u;
}
// bijective XCD-aware block swizzle (m204 variant)
__device__ __forceinline__ int xcd_swz(int orig, int nwg) {
    int q = nwg >> 3, r = nwg & 7;
    int xcd = orig & 7, pos = orig >> 3;
    return (xcd < r ? xcd * (q + 1) : r * (q + 1) + (xcd - r) * q) + pos;
}
// async 16B global -> LDS (direct-to-shared DMA)
__device__ __forceinline__ void gload_lds16(const void* g, void* l) {
    __builtin_amdgcn_global_load_lds(
        (const __attribute__((address_space(1))) unsigned int*)g,
        (__attribute__((address_space(3))) unsigned int*)l, 16, 0, 0);
}

// ---------------------------------------------------------------------------
// Kernel 1: time embedding -> bf16 xeb[(N+1)][8] = {feat, sin*3, cos*3, 0}
// ---------------------------------------------------------------------------
__global__ void embed_kernel(const float* __restrict__ feat,
                             const int* __restrict__ t,
                             unsigned short* __restrict__ xeb) {
    int i = blockIdx.x * blockDim.x + threadIdx.x;
    if (i > N_VOX) return;
    union { unsigned short u[8]; int4 v; } o;
    if (i == N_VOX) {
        o.v = make_int4(0, 0, 0, 0);
    } else {
        o.u[0] = f2bf(feat[i]);
        float tf = (float)t[i];
#pragma unroll
        for (int kk = 0; kk < 3; ++kk) {
            float freq = (float)M_PI * (float)(1 << kk);
            float ang = tf * freq;
            o.u[1 + kk] = f2bf(sinf(ang));
            o.u[4 + kk] = f2bf(cosf(ang));
        }
        o.u[7] = 0;
    }
    *(int4*)(xeb + (size_t)i * 8) = o.v;
}

// ---------------------------------------------------------------------------
// Weight repacks to MFMA-fragment-linear bf16 (B-operand layout).
// ---------------------------------------------------------------------------
__global__ void convert_w1(const float* __restrict__ W1,
                           unsigned short* __restrict__ W1f) {
    int g = blockIdx.x * 256 + threadIdx.x;
    if (g >= 7 * 8 * 64) return;
    int l = g & 63;
    int rest = g >> 6;
    int nf = rest & 7;
    int kk = rest >> 3;
    int o = kk * 4 + (l >> 4);
    int co = nf * 16 + (l & 15);
    union { unsigned short u[8]; int4 v; } out;
#pragma unroll
    for (int j = 0; j < 8; ++j) {
        float w = 0.f;
        if (o < KOFF && j < 7) w = W1[((size_t)o * 7 + j) * CCH + co];
        out.u[j] = f2bf(w);
    }
    *(int4*)(W1f + (size_t)g * 8) = out.v;
}

__global__ void convert_w2(const float* __restrict__ W2,
                           unsigned short* __restrict__ W2f) {
    int g = blockIdx.x * 256 + threadIdx.x;
    int l = g & 63;
    int rest = g >> 6;
    int nf = rest & 7;
    int kkk = rest >> 3;
    int k = kkk >> 2, kk = kkk & 3;
    int ci0 = kk * 32 + (l >> 4) * 8;
    int co = nf * 16 + (l & 15);
    union { unsigned short u[8]; int4 v; } out;
#pragma unroll
    for (int j = 0; j < 8; ++j)
        out.u[j] = f2bf(W2[((size_t)k * CCH + ci0 + j) * CCH + co]);
    *(int4*)(W2f + (size_t)g * 8) = out.v;
}

__global__ void convert_w3(const float* __restrict__ W3,
                           unsigned short* __restrict__ W3f) {
    int g = blockIdx.x * 256 + threadIdx.x;
    if (g >= 4 * 8 * 64) return;
    int l = g & 63;
    int rest = g >> 6;
    int nf = rest & 7;
    int kk = rest >> 3;
    int ci0 = kk * 32 + (l >> 4) * 8;
    int co = nf * 16 + (l & 15);
    union { unsigned short u[8]; int4 v; } out;
#pragma unroll
    for (int j = 0; j < 8; ++j)
        out.u[j] = f2bf(W3[(size_t)(ci0 + j) * CCH + co]);
    *(int4*)(W3f + (size_t)g * 8) = out.v;
}

// ---------------------------------------------------------------------------
// Kernel 2: conv1 via MFMA. 128 vox x 128 ch per block, K = 7 steps of 32.
// ---------------------------------------------------------------------------
__global__ __launch_bounds__(256) void conv1_mfma(
    const unsigned short* __restrict__ xeb, const int* __restrict__ nidx,
    const unsigned short* __restrict__ W1f, const float* __restrict__ b1,
    unsigned short* __restrict__ h1b) {
    __shared__ int4 bufmem[2048];
    __shared__ int idxAll[128 * 28];

    int tid = threadIdx.x;
    int l = tid & 63, w = tid >> 6;
    int mw = w >> 1, nwv = w & 1;
    int wg = xcd_swz(blockIdx.x, gridDim.x);
    int v0 = wg * 128;

    for (int g = tid; g < KOFF * 128; g += 256) {
        int k = g >> 7, vi = g & 127;
        int v = v0 + vi;
        idxAll[vi * 28 + k] = (v < N_VOX) ? nidx[(size_t)k * N_VOX + v] : N_VOX;
    }
    if (tid < 128) idxAll[tid * 28 + 27] = N_VOX;
    __syncthreads();

    f32x4 acc[4][4];
#pragma unroll
    for (int m = 0; m < 4; ++m)
#pragma unroll
        for (int n = 0; n < 4; ++n) acc[m][n] = (f32x4)0.f;

    {
        int4 g0[2]; int rr[2], cc[2];
#pragma unroll
        for (int u = 0; u < 2; ++u) {
            int q = u * 256 + tid;
            int r = q >> 2, oo = q & 3;
            int idx = idxAll[r * 28 + oo];
            g0[u] = *(const int4*)(xeb + (size_t)idx * 8);
            rr[u] = r; cc[u] = oo ^ (r & 3);
        }
#pragma unroll
        for (int u = 0; u < 2; ++u) bufmem[rr[u] * 5 + cc[u]] = g0[u];
    }
    __syncthreads();

    for (int kk = 0; kk < 7; ++kk) {
        int cur = kk & 1;
        int4 gg[2]; int rr[2], cc[2];
        if (kk < 6) {
#pragma unroll
            for (int u = 0; u < 2; ++u) {
                int q = u * 256 + tid;
                int r = q >> 2, oo = q & 3;
                int idx = idxAll[r * 28 + (kk + 1) * 4 + oo];
                gg[u] = *(const int4*)(xeb + (size_t)idx * 8);
                rr[u] = r; cc[u] = oo ^ (r & 3);
            }
        }
        bf16x8 a[4], b[4];
#pragma unroll
        for (int n = 0; n < 4; ++n) {
            int nf = nwv * 4 + n;
            b[n] = *(const bf16x8*)(W1f + ((size_t)(kk * 8 + nf) * 64 + l) * 8);
        }
#pragma unroll
        for (int m = 0; m < 4; ++m) {
            int r = mw * 64 + m * 16 + (l & 15);
            int c = l >> 4;
            a[m] = *(const bf16x8*)&bufmem[cur * 640 + r * 5 + (c ^ (r & 3))];
        }
#pragma unroll
        for (int m = 0; m < 4; ++m)
#pragma unroll
            for (int n = 0; n < 4; ++n)
                acc[m][n] = __builtin_amdgcn_mfma_f32_16x16x32_bf16(
                    a[m], b[n], acc[m][n], 0, 0, 0);
        if (kk < 6) {
#pragma unroll
            for (int u = 0; u < 2; ++u)
                bufmem[(cur ^ 1) * 640 + rr[u] * 5 + cc[u]] = gg[u];
        }
        __syncthreads();
    }

    float bias[4];
#pragma unroll
    for (int n = 0; n < 4; ++n) bias[n] = b1[nwv * 64 + n * 16 + (l & 15)];
    unsigned short* H16 = (unsigned short*)bufmem;
#pragma unroll
    for (int m = 0; m < 4; ++m) {
        int rbase = mw * 64 + m * 16 + (l >> 4) * 4;
#pragma unroll
        for (int n = 0; n < 4; ++n) {
            int ch = nwv * 64 + n * 16 + (l & 15);
            int c = ch >> 3;
            f32x4 d = acc[m][n];
#pragma unroll
            for (int ri = 0; ri < 4; ++ri) {
                int r = rbase + ri;
                int s = (c & 8) | ((c & 7) ^ (r & 7));
                H16[r * 128 + s * 8 + (ch & 7)] = f2bf(silu_f(d[ri] + bias[n]));
            }
        }
    }
    __syncthreads();
#pragma unroll
    for (int u = 0; u < 8; ++u) {
        int q = u * 256 + tid;
        int r = q >> 4, s = q & 15;
        int c = (s & 8) | ((s & 7) ^ (r & 7));
        int v = v0 + r;
        if (v < N_VOX)
            *(int4*)(h1b + (size_t)v * CCH + c * 8) = bufmem[r * 16 + s];
    }
    if (blockIdx.x == 0 && tid < 16)
        *(int4*)(h1b + (size_t)N_VOX * CCH + tid * 8) = make_int4(0, 0, 0, 0);
}

// ---------------------------------------------------------------------------
// Kernel 3: conv2 = r12 structure (BM=256, BK=64, frag-tiled conflict-free
// LDS, T3-min schedule) but with 512 threads / 8 waves (4mw x 2nwv), per-wave
// 64x64 tile acc[4][4]=64 VGPR: doubles waves/CU (8->16) and halves each
// wave's serial MFMA chain to attack the latency-bound 63% idle measured in
// r12 (nothing saturated: LDS 21%, L2 33%, HBM 3% of ceilings).
// ---------------------------------------------------------------------------
#define STAGE_S(buf, sq, ib) {                                             \
    _Pragma("unroll") for (int _u = 0; _u < 4; ++_u) {                     \
        int _q = _u * 512 + tid;                                           \
        int _row = ((_q >> 7) << 4) | (_q & 15);                           \
        int _hi = (_q >> 4) & 3;                                           \
        int _kk = (_q >> 6) & 1;                                           \
        int _idx = idxbuf[ib][_row];                                       \
        gload_lds16((const char*)h1b + ((size_t)(unsigned)_idx << 8) +     \
                        ((sq) & 1) * 128 + _kk * 64 + _hi * 16,            \
                    (void*)&Abuf[buf][_q]);                                \
    }                                                                      \
}

#define LOADB_S(dst, sq) {                                                 \
    const unsigned short* _wb = W2f + (size_t)((sq) >> 1) * 16384 +        \
                                (size_t)((sq) & 1) * 2 * 4096;             \
    _Pragma("unroll") for (int _kk = 0; _kk < 2; ++_kk)                    \
        _Pragma("unroll") for (int _n = 0; _n < 4; ++_n)                   \
            dst[_kk][_n] = *(const bf16x8*)(_wb +                          \
                ((size_t)(_kk * 8 + nwv * 4 + _n) * 64 + l) * 8);          \
}

#define MFMA_S(cur, bfr) {                                                 \
    _Pragma("unroll") for (int _kk = 0; _kk < 2; ++_kk) {                  \
        bf16x8 _a[4];                                                      \
        _Pragma("unroll") for (int _m = 0; _m < 4; ++_m) {                 \
            int _R = mw * 4 + _m;                                          \
            _a[_m] = *(const bf16x8*)&Abuf[cur][((_R * 2 + _kk) << 6) + l];\
        }                                                                  \
        __builtin_amdgcn_s_setprio(1);                                     \
        _Pragma("unroll") for (int _m = 0; _m < 4; ++_m)                   \
            _Pragma("unroll") for (int _n = 0; _n < 4; ++_n)               \
                acc[_m][_n] = __builtin_amdgcn_mfma_f32_16x16x32_bf16(     \
                    _a[_m], bfr[_kk][_n], acc[_m][_n], 0, 0, 0);           \
        __builtin_amdgcn_s_setprio(0);                                     \
    }                                                                      \
}

#define STEP_S(SQ, CUR, DO_STAGE, DO_IDX) {                                \
    bf16x8 bfr[2][4];                                                      \
    LOADB_S(bfr, SQ);                                                      \
    __builtin_amdgcn_sched_barrier(0);                                     \
    if (DO_STAGE) { STAGE_S((CUR) ^ 1, (SQ) + 1, ((((SQ) + 1) >> 1) & 1)); }\
    if (DO_IDX) {                                                          \
        if (tid < 256) {                                                   \
            int _k1 = ((SQ) >> 1) + 1;                                     \
            int _v = v0 + tid;                                             \
            idxbuf[_k1 & 1][tid] =                                         \
                (_v < N_VOX) ? nidx[(size_t)_k1 * N_VOX + _v] : N_VOX;     \
        }                                                                  \
    }                                                                      \
    __builtin_amdgcn_sched_barrier(0);                                     \
    MFMA_S(CUR, bfr);                                                      \
    asm volatile("s_waitcnt vmcnt(0)" ::: "memory");                       \
    __builtin_amdgcn_s_barrier();                                          \
}

__global__ __launch_bounds__(512, 4) void conv2_mfma(
    const unsigned short* __restrict__ h1b, const int* __restrict__ nidx,
    const unsigned short* __restrict__ W2f, const float* __restrict__ b2,
    const unsigned short* __restrict__ W3f, const float* __restrict__ b3,
    const float* __restrict__ W4, const float* __restrict__ b4,
    float* __restrict__ out) {
    __shared__ int4 Abuf[2][2048];   // 64 KB, frag-tiled BK=64 A-tiles
    __shared__ int idxbuf[2][256];   // 2 KB, per-k gather indices
    __shared__ float Osum[512];      // 2 KB tail reduce

    int tid = threadIdx.x;
    int l = tid & 63, w = tid >> 6;
    int mw = w >> 1, nwv = w & 1;    // mw 0..3, nwv 0..1
    int wg = xcd_swz(blockIdx.x, gridDim.x);
    int v0 = wg * 256;

    f32x4 acc[4][4];
#pragma unroll
    for (int m = 0; m < 4; ++m)
#pragma unroll
        for (int n = 0; n < 4; ++n) acc[m][n] = (f32x4)0.f;

    // prologue: idx(k=0) -> sync -> stage step0 + idx(k=1) -> drain -> sync
    if (tid < 256) {
        int v = v0 + tid;
        idxbuf[0][tid] = (v < N_VOX) ? nidx[v] : N_VOX;
    }
    __syncthreads();
    STAGE_S(0, 0, 0);
    if (tid < 256) {
        int v = v0 + tid;
        idxbuf[1][tid] = (v < N_VOX) ? nidx[(size_t)N_VOX + v] : N_VOX;
    }
    asm volatile("s_waitcnt vmcnt(0)" ::: "memory");
    __syncthreads();

    for (int sp = 0; sp < 52; sp += 2) {
        STEP_S(sp, 0, true, ((sp >> 1) + 1 < KOFF));
        STEP_S(sp + 1, 1, true, false);
    }
    STEP_S(52, 0, true, false);    // stages step 53
    STEP_S(53, 1, false, false);   // last: no staging

    // ---- fused tail: H = bf16(silu(acc+b2)) -> LDS; P = H @ W3; out ----
    float bias2[4];
#pragma unroll
    for (int n = 0; n < 4; ++n) bias2[n] = b2[nwv * 64 + n * 16 + (l & 15)];
    unsigned short* H16 = (unsigned short*)&Abuf[0][0];   // 256x128 = 64 KB
#pragma unroll
    for (int m = 0; m < 4; ++m) {
        int rbase = mw * 64 + m * 16 + (l >> 4) * 4;
#pragma unroll
        for (int n = 0; n < 4; ++n) {
            int ch = nwv * 64 + n * 16 + (l & 15);
            int c = ch >> 3;
            f32x4 d = acc[m][n];
#pragma unroll
            for (int ri = 0; ri < 4; ++ri) {
                int r = rbase + ri;
                int s = (c & 8) | ((c & 7) ^ (r & 7));
                H16[r * 128 + s * 8 + (ch & 7)] = f2bf(silu_f(d[ri] + bias2[n]));
            }
        }
    }
    __syncthreads();

    f32x4 p[4][4];
#pragma unroll
    for (int m = 0; m < 4; ++m)
#pragma unroll
        for (int n = 0; n < 4; ++n) p[m][n] = (f32x4)0.f;
#pragma unroll
    for (int kk = 0; kk < 4; ++kk) {
        bf16x8 a[4], b[4];
#pragma unroll
        for (int n = 0; n < 4; ++n) {
            int nf = nwv * 4 + n;
            b[n] = *(const bf16x8*)(W3f + ((size_t)(kk * 8 + nf) * 64 + l) * 8);
        }
#pragma unroll
        for (int m = 0; m < 4; ++m) {
            int r = mw * 64 + m * 16 + (l & 15);
            int c = kk * 4 + (l >> 4);
            int s = (c & 8) | ((c & 7) ^ (r & 7));
            a[m] = *(const bf16x8*)&H16[r * 128 + s * 8];
        }
#pragma unroll
        for (int m = 0; m < 4; ++m)
#pragma unroll
            for (int n = 0; n < 4; ++n)
                p[m][n] = __builtin_amdgcn_mfma_f32_16x16x32_bf16(
                    a[m], b[n], p[m][n], 0, 0, 0);
    }

    float w4v[4], b3v[4];
#pragma unroll
    for (int n = 0; n < 4; ++n) {
        int ch = nwv * 64 + n * 16 + (l & 15);
        w4v[n] = W4[ch];
        b3v[n] = b3[ch];
    }
#pragma unroll
    for (int m = 0; m < 4; ++m) {
        float po[4] = {0.f, 0.f, 0.f, 0.f};
#pragma unroll
        for (int n = 0; n < 4; ++n) {
            f32x4 d = p[m][n];
#pragma unroll
            for (int ri = 0; ri < 4; ++ri)
                po[ri] += silu_f(d[ri] + b3v[n]) * w4v[n];
        }
#pragma unroll
        for (int off = 1; off < 16; off <<= 1)
#pragma unroll
            for (int ri = 0; ri < 4; ++ri)
                po[ri] += __shfl_xor(po[ri], off, 64);
        if ((l & 15) == 0) {
            int rbase = mw * 64 + m * 16 + (l >> 4) * 4;
#pragma unroll
            for (int ri = 0; ri < 4; ++ri)
                Osum[nwv * 256 + rbase + ri] = po[ri];
        }
    }
    __syncthreads();
    if (tid < 256) {
        int v = v0 + tid;
        if (v < N_VOX) out[v] = Osum[tid] + Osum[256 + tid] + b4[0];
    }
}

// ---------------------------------------------------------------------------
extern "C" void kernel_launch(void* const* d_in, const int* in_sizes, int n_in,
                              void* d_out, int out_size, void* d_ws,
                              size_t ws_size, hipStream_t stream) {
    const float* feat = (const float*)d_in[0];
    const int* t      = (const int*)d_in[1];
    const int* nidx   = (const int*)d_in[2];
    const float* W1   = (const float*)d_in[3];
    const float* b1   = (const float*)d_in[4];
    const float* W2   = (const float*)d_in[5];
    const float* b2   = (const float*)d_in[6];
    const float* W3   = (const float*)d_in[7];
    const float* b3   = (const float*)d_in[8];
    const float* W4   = (const float*)d_in[9];
    const float* b4   = (const float*)d_in[10];
    float* out = (float*)d_out;

    char* ws = (char*)d_ws;
    size_t off = 0;
    unsigned short* xeb = (unsigned short*)(ws + off);
    off += ((size_t)(N_VOX + 1) * 8 * 2 + 255) & ~(size_t)255;
    unsigned short* h1b = (unsigned short*)(ws + off);
    off += ((size_t)(N_VOX + 1) * CCH * 2 + 255) & ~(size_t)255;
    unsigned short* W1f = (unsigned short*)(ws + off);
    off += ((size_t)7 * 8 * 64 * 8 * 2 + 255) & ~(size_t)255;
    unsigned short* W2f = (unsigned short*)(ws + off);
    off += ((size_t)(KOFF + 1) * 4 * 8 * 64 * 8 * 2 + 255) & ~(size_t)255;
    unsigned short* W3f = (unsigned short*)(ws + off);

    int grid1 = (N_VOX + 127) / 128;
    int grid2 = (N_VOX + 255) / 256;
    embed_kernel<<<(N_VOX + 1 + 255) / 256, 256, 0, stream>>>(feat, t, xeb);
    convert_w1<<<(7 * 8 * 64 + 255) / 256, 256, 0, stream>>>(W1, W1f);
    convert_w2<<<(KOFF * 4 * 8 * 64) / 256, 256, 0, stream>>>(W2, W2f);
    convert_w3<<<(4 * 8 * 64 + 255) / 256, 256, 0, stream>>>(W3, W3f);
    conv1_mfma<<<grid1, 256, 0, stream>>>(xeb, nidx, W1f, b1, h1b);
    conv2_mfma<<<grid2, 512, 0, stream>>>(h1b, nidx, W2f, b2, W3f, b3, W4, b4, out);
}

// Round 15
// 418.750 us; speedup vs baseline: 1.4178x; 1.4178x over previous
//
#include <hip/hip_runtime.h>
#include <math.h>

#define N_VOX 200000
#define CCH   128
#define KOFF  27

typedef __attribute__((ext_vector_type(8))) short bf16x8;
typedef __attribute__((ext_vector_type(4))) float f32x4;

__device__ __forceinline__ float silu_f(float x) {
    return x / (1.0f + expf(-x));
}
__device__ __forceinline__ unsigned short f2bf(float x) {
    unsigned int u = __float_as_uint(x);
    u = (u + 0x7FFFu + ((u >> 16) & 1u)) >> 16;
    return (unsigned short)u;
}
// bijective XCD-aware block swizzle (m204 variant)
__device__ __forceinline__ int xcd_swz(int orig, int nwg) {
    int q = nwg >> 3, r = nwg & 7;
    int xcd = orig & 7, pos = orig >> 3;
    return (xcd < r ? xcd * (q + 1) : r * (q + 1) + (xcd - r) * q) + pos;
}
// async 16B global -> LDS (direct-to-shared DMA)
__device__ __forceinline__ void gload_lds16(const void* g, void* l) {
    __builtin_amdgcn_global_load_lds(
        (const __attribute__((address_space(1))) unsigned int*)g,
        (__attribute__((address_space(3))) unsigned int*)l, 16, 0, 0);
}

// ---------------------------------------------------------------------------
// Kernel 1: time embedding -> bf16 xeb[(N+1)][8] = {feat, sin*3, cos*3, 0}
// ---------------------------------------------------------------------------
__global__ void embed_kernel(const float* __restrict__ feat,
                             const int* __restrict__ t,
                             unsigned short* __restrict__ xeb) {
    int i = blockIdx.x * blockDim.x + threadIdx.x;
    if (i > N_VOX) return;
    union { unsigned short u[8]; int4 v; } o;
    if (i == N_VOX) {
        o.v = make_int4(0, 0, 0, 0);
    } else {
        o.u[0] = f2bf(feat[i]);
        float tf = (float)t[i];
#pragma unroll
        for (int kk = 0; kk < 3; ++kk) {
            float freq = (float)M_PI * (float)(1 << kk);
            float ang = tf * freq;
            o.u[1 + kk] = f2bf(sinf(ang));
            o.u[4 + kk] = f2bf(cosf(ang));
        }
        o.u[7] = 0;
    }
    *(int4*)(xeb + (size_t)i * 8) = o.v;
}

// ---------------------------------------------------------------------------
// Weight repacks to MFMA-fragment-linear bf16 (B-operand layout).
// ---------------------------------------------------------------------------
__global__ void convert_w1(const float* __restrict__ W1,
                           unsigned short* __restrict__ W1f) {
    int g = blockIdx.x * 256 + threadIdx.x;
    if (g >= 7 * 8 * 64) return;
    int l = g & 63;
    int rest = g >> 6;
    int nf = rest & 7;
    int kk = rest >> 3;
    int o = kk * 4 + (l >> 4);
    int co = nf * 16 + (l & 15);
    union { unsigned short u[8]; int4 v; } out;
#pragma unroll
    for (int j = 0; j < 8; ++j) {
        float w = 0.f;
        if (o < KOFF && j < 7) w = W1[((size_t)o * 7 + j) * CCH + co];
        out.u[j] = f2bf(w);
    }
    *(int4*)(W1f + (size_t)g * 8) = out.v;
}

__global__ void convert_w2(const float* __restrict__ W2,
                           unsigned short* __restrict__ W2f) {
    int g = blockIdx.x * 256 + threadIdx.x;
    int l = g & 63;
    int rest = g >> 6;
    int nf = rest & 7;
    int kkk = rest >> 3;
    int k = kkk >> 2, kk = kkk & 3;
    int ci0 = kk * 32 + (l >> 4) * 8;
    int co = nf * 16 + (l & 15);
    union { unsigned short u[8]; int4 v; } out;
#pragma unroll
    for (int j = 0; j < 8; ++j)
        out.u[j] = f2bf(W2[((size_t)k * CCH + ci0 + j) * CCH + co]);
    *(int4*)(W2f + (size_t)g * 8) = out.v;
}

__global__ void convert_w3(const float* __restrict__ W3,
                           unsigned short* __restrict__ W3f) {
    int g = blockIdx.x * 256 + threadIdx.x;
    if (g >= 4 * 8 * 64) return;
    int l = g & 63;
    int rest = g >> 6;
    int nf = rest & 7;
    int kk = rest >> 3;
    int ci0 = kk * 32 + (l >> 4) * 8;
    int co = nf * 16 + (l & 15);
    union { unsigned short u[8]; int4 v; } out;
#pragma unroll
    for (int j = 0; j < 8; ++j)
        out.u[j] = f2bf(W3[(size_t)(ci0 + j) * CCH + co]);
    *(int4*)(W3f + (size_t)g * 8) = out.v;
}

// ---------------------------------------------------------------------------
// Kernel 2: conv1 via MFMA. 128 vox x 128 ch per block, K = 7 steps of 32.
// ---------------------------------------------------------------------------
__global__ __launch_bounds__(256) void conv1_mfma(
    const unsigned short* __restrict__ xeb, const int* __restrict__ nidx,
    const unsigned short* __restrict__ W1f, const float* __restrict__ b1,
    unsigned short* __restrict__ h1b) {
    __shared__ int4 bufmem[2048];
    __shared__ int idxAll[128 * 28];

    int tid = threadIdx.x;
    int l = tid & 63, w = tid >> 6;
    int mw = w >> 1, nwv = w & 1;
    int wg = xcd_swz(blockIdx.x, gridDim.x);
    int v0 = wg * 128;

    for (int g = tid; g < KOFF * 128; g += 256) {
        int k = g >> 7, vi = g & 127;
        int v = v0 + vi;
        idxAll[vi * 28 + k] = (v < N_VOX) ? nidx[(size_t)k * N_VOX + v] : N_VOX;
    }
    if (tid < 128) idxAll[tid * 28 + 27] = N_VOX;
    __syncthreads();

    f32x4 acc[4][4];
#pragma unroll
    for (int m = 0; m < 4; ++m)
#pragma unroll
        for (int n = 0; n < 4; ++n) acc[m][n] = (f32x4)0.f;

    {
        int4 g0[2]; int rr[2], cc[2];
#pragma unroll
        for (int u = 0; u < 2; ++u) {
            int q = u * 256 + tid;
            int r = q >> 2, oo = q & 3;
            int idx = idxAll[r * 28 + oo];
            g0[u] = *(const int4*)(xeb + (size_t)idx * 8);
            rr[u] = r; cc[u] = oo ^ (r & 3);
        }
#pragma unroll
        for (int u = 0; u < 2; ++u) bufmem[rr[u] * 5 + cc[u]] = g0[u];
    }
    __syncthreads();

    for (int kk = 0; kk < 7; ++kk) {
        int cur = kk & 1;
        int4 gg[2]; int rr[2], cc[2];
        if (kk < 6) {
#pragma unroll
            for (int u = 0; u < 2; ++u) {
                int q = u * 256 + tid;
                int r = q >> 2, oo = q & 3;
                int idx = idxAll[r * 28 + (kk + 1) * 4 + oo];
                gg[u] = *(const int4*)(xeb + (size_t)idx * 8);
                rr[u] = r; cc[u] = oo ^ (r & 3);
            }
        }
        bf16x8 a[4], b[4];
#pragma unroll
        for (int n = 0; n < 4; ++n) {
            int nf = nwv * 4 + n;
            b[n] = *(const bf16x8*)(W1f + ((size_t)(kk * 8 + nf) * 64 + l) * 8);
        }
#pragma unroll
        for (int m = 0; m < 4; ++m) {
            int r = mw * 64 + m * 16 + (l & 15);
            int c = l >> 4;
            a[m] = *(const bf16x8*)&bufmem[cur * 640 + r * 5 + (c ^ (r & 3))];
        }
#pragma unroll
        for (int m = 0; m < 4; ++m)
#pragma unroll
            for (int n = 0; n < 4; ++n)
                acc[m][n] = __builtin_amdgcn_mfma_f32_16x16x32_bf16(
                    a[m], b[n], acc[m][n], 0, 0, 0);
        if (kk < 6) {
#pragma unroll
            for (int u = 0; u < 2; ++u)
                bufmem[(cur ^ 1) * 640 + rr[u] * 5 + cc[u]] = gg[u];
        }
        __syncthreads();
    }

    float bias[4];
#pragma unroll
    for (int n = 0; n < 4; ++n) bias[n] = b1[nwv * 64 + n * 16 + (l & 15)];
    unsigned short* H16 = (unsigned short*)bufmem;
#pragma unroll
    for (int m = 0; m < 4; ++m) {
        int rbase = mw * 64 + m * 16 + (l >> 4) * 4;
#pragma unroll
        for (int n = 0; n < 4; ++n) {
            int ch = nwv * 64 + n * 16 + (l & 15);
            int c = ch >> 3;
            f32x4 d = acc[m][n];
#pragma unroll
            for (int ri = 0; ri < 4; ++ri) {
                int r = rbase + ri;
                int s = (c & 8) | ((c & 7) ^ (r & 7));
                H16[r * 128 + s * 8 + (ch & 7)] = f2bf(silu_f(d[ri] + bias[n]));
            }
        }
    }
    __syncthreads();
#pragma unroll
    for (int u = 0; u < 8; ++u) {
        int q = u * 256 + tid;
        int r = q >> 4, s = q & 15;
        int c = (s & 8) | ((s & 7) ^ (r & 7));
        int v = v0 + r;
        if (v < N_VOX)
            *(int4*)(h1b + (size_t)v * CCH + c * 8) = bufmem[r * 16 + s];
    }
    if (blockIdx.x == 0 && tid < 16)
        *(int4*)(h1b + (size_t)N_VOX * CCH + tid * 8) = make_int4(0, 0, 0, 0);
}

// ---------------------------------------------------------------------------
// Kernel 3: conv2, r14 structure with the spill fixed: __launch_bounds__
// (512, 2) -> VGPR budget >=128 (per-wave body is r7's shape, ~108 VGPR,
// no spill), LDS 68KB still allows 2 blocks/CU = 16 waves/CU (2x r12).
// BM=256, BK=64, 8 waves (4mw x 2nwv), per-wave 64x64 acc[4][4].
// ---------------------------------------------------------------------------
#define STAGE_S(buf, sq, ib) {                                             \
    _Pragma("unroll") for (int _u = 0; _u < 4; ++_u) {                     \
        int _q = _u * 512 + tid;                                           \
        int _row = ((_q >> 7) << 4) | (_q & 15);                           \
        int _hi = (_q >> 4) & 3;                                           \
        int _kk = (_q >> 6) & 1;                                           \
        int _idx = idxbuf[ib][_row];                                       \
        gload_lds16((const char*)h1b + ((size_t)(unsigned)_idx << 8) +     \
                        ((sq) & 1) * 128 + _kk * 64 + _hi * 16,            \
                    (void*)&Abuf[buf][_q]);                                \
    }                                                                      \
}

#define LOADB_S(dst, sq) {                                                 \
    const unsigned short* _wb = W2f + (size_t)((sq) >> 1) * 16384 +        \
                                (size_t)((sq) & 1) * 2 * 4096;             \
    _Pragma("unroll") for (int _kk = 0; _kk < 2; ++_kk)                    \
        _Pragma("unroll") for (int _n = 0; _n < 4; ++_n)                   \
            dst[_kk][_n] = *(const bf16x8*)(_wb +                          \
                ((size_t)(_kk * 8 + nwv * 4 + _n) * 64 + l) * 8);          \
}

#define MFMA_S(cur, bfr) {                                                 \
    _Pragma("unroll") for (int _kk = 0; _kk < 2; ++_kk) {                  \
        bf16x8 _a[4];                                                      \
        _Pragma("unroll") for (int _m = 0; _m < 4; ++_m) {                 \
            int _R = mw * 4 + _m;                                          \
            _a[_m] = *(const bf16x8*)&Abuf[cur][((_R * 2 + _kk) << 6) + l];\
        }                                                                  \
        __builtin_amdgcn_s_setprio(1);                                     \
        _Pragma("unroll") for (int _m = 0; _m < 4; ++_m)                   \
            _Pragma("unroll") for (int _n = 0; _n < 4; ++_n)               \
                acc[_m][_n] = __builtin_amdgcn_mfma_f32_16x16x32_bf16(     \
                    _a[_m], bfr[_kk][_n], acc[_m][_n], 0, 0, 0);           \
        __builtin_amdgcn_s_setprio(0);                                     \
    }                                                                      \
}

#define STEP_S(SQ, CUR, DO_STAGE, DO_IDX) {                                \
    bf16x8 bfr[2][4];                                                      \
    LOADB_S(bfr, SQ);                                                      \
    __builtin_amdgcn_sched_barrier(0);                                     \
    if (DO_STAGE) { STAGE_S((CUR) ^ 1, (SQ) + 1, ((((SQ) + 1) >> 1) & 1)); }\
    if (DO_IDX) {                                                          \
        if (tid < 256) {                                                   \
            int _k1 = ((SQ) >> 1) + 1;                                     \
            int _v = v0 + tid;                                             \
            idxbuf[_k1 & 1][tid] =                                         \
                (_v < N_VOX) ? nidx[(size_t)_k1 * N_VOX + _v] : N_VOX;     \
        }                                                                  \
    }                                                                      \
    __builtin_amdgcn_sched_barrier(0);                                     \
    MFMA_S(CUR, bfr);                                                      \
    asm volatile("s_waitcnt vmcnt(0)" ::: "memory");                       \
    __builtin_amdgcn_s_barrier();                                          \
}

__global__ __launch_bounds__(512, 2) void conv2_mfma(
    const unsigned short* __restrict__ h1b, const int* __restrict__ nidx,
    const unsigned short* __restrict__ W2f, const float* __restrict__ b2,
    const unsigned short* __restrict__ W3f, const float* __restrict__ b3,
    const float* __restrict__ W4, const float* __restrict__ b4,
    float* __restrict__ out) {
    __shared__ int4 Abuf[2][2048];   // 64 KB, frag-tiled BK=64 A-tiles
    __shared__ int idxbuf[2][256];   // 2 KB, per-k gather indices
    __shared__ float Osum[512];      // 2 KB tail reduce

    int tid = threadIdx.x;
    int l = tid & 63, w = tid >> 6;
    int mw = w >> 1, nwv = w & 1;    // mw 0..3, nwv 0..1
    int wg = xcd_swz(blockIdx.x, gridDim.x);
    int v0 = wg * 256;

    f32x4 acc[4][4];
#pragma unroll
    for (int m = 0; m < 4; ++m)
#pragma unroll
        for (int n = 0; n < 4; ++n) acc[m][n] = (f32x4)0.f;

    // prologue: idx(k=0) -> sync -> stage step0 + idx(k=1) -> drain -> sync
    if (tid < 256) {
        int v = v0 + tid;
        idxbuf[0][tid] = (v < N_VOX) ? nidx[v] : N_VOX;
    }
    __syncthreads();
    STAGE_S(0, 0, 0);
    if (tid < 256) {
        int v = v0 + tid;
        idxbuf[1][tid] = (v < N_VOX) ? nidx[(size_t)N_VOX + v] : N_VOX;
    }
    asm volatile("s_waitcnt vmcnt(0)" ::: "memory");
    __syncthreads();

    for (int sp = 0; sp < 52; sp += 2) {
        STEP_S(sp, 0, true, ((sp >> 1) + 1 < KOFF));
        STEP_S(sp + 1, 1, true, false);
    }
    STEP_S(52, 0, true, false);    // stages step 53
    STEP_S(53, 1, false, false);   // last: no staging

    // ---- fused tail: H = bf16(silu(acc+b2)) -> LDS; P = H @ W3; out ----
    float bias2[4];
#pragma unroll
    for (int n = 0; n < 4; ++n) bias2[n] = b2[nwv * 64 + n * 16 + (l & 15)];
    unsigned short* H16 = (unsigned short*)&Abuf[0][0];   // 256x128 = 64 KB
#pragma unroll
    for (int m = 0; m < 4; ++m) {
        int rbase = mw * 64 + m * 16 + (l >> 4) * 4;
#pragma unroll
        for (int n = 0; n < 4; ++n) {
            int ch = nwv * 64 + n * 16 + (l & 15);
            int c = ch >> 3;
            f32x4 d = acc[m][n];
#pragma unroll
            for (int ri = 0; ri < 4; ++ri) {
                int r = rbase + ri;
                int s = (c & 8) | ((c & 7) ^ (r & 7));
                H16[r * 128 + s * 8 + (ch & 7)] = f2bf(silu_f(d[ri] + bias2[n]));
            }
        }
    }
    __syncthreads();

    f32x4 p[4][4];
#pragma unroll
    for (int m = 0; m < 4; ++m)
#pragma unroll
        for (int n = 0; n < 4; ++n) p[m][n] = (f32x4)0.f;
#pragma unroll
    for (int kk = 0; kk < 4; ++kk) {
        bf16x8 a[4], b[4];
#pragma unroll
        for (int n = 0; n < 4; ++n) {
            int nf = nwv * 4 + n;
            b[n] = *(const bf16x8*)(W3f + ((size_t)(kk * 8 + nf) * 64 + l) * 8);
        }
#pragma unroll
        for (int m = 0; m < 4; ++m) {
            int r = mw * 64 + m * 16 + (l & 15);
            int c = kk * 4 + (l >> 4);
            int s = (c & 8) | ((c & 7) ^ (r & 7));
            a[m] = *(const bf16x8*)&H16[r * 128 + s * 8];
        }
#pragma unroll
        for (int m = 0; m < 4; ++m)
#pragma unroll
            for (int n = 0; n < 4; ++n)
                p[m][n] = __builtin_amdgcn_mfma_f32_16x16x32_bf16(
                    a[m], b[n], p[m][n], 0, 0, 0);
    }

    float w4v[4], b3v[4];
#pragma unroll
    for (int n = 0; n < 4; ++n) {
        int ch = nwv * 64 + n * 16 + (l & 15);
        w4v[n] = W4[ch];
        b3v[n] = b3[ch];
    }
#pragma unroll
    for (int m = 0; m < 4; ++m) {
        float po[4] = {0.f, 0.f, 0.f, 0.f};
#pragma unroll
        for (int n = 0; n < 4; ++n) {
            f32x4 d = p[m][n];
#pragma unroll
            for (int ri = 0; ri < 4; ++ri)
                po[ri] += silu_f(d[ri] + b3v[n]) * w4v[n];
        }
#pragma unroll
        for (int off = 1; off < 16; off <<= 1)
#pragma unroll
            for (int ri = 0; ri < 4; ++ri)
                po[ri] += __shfl_xor(po[ri], off, 64);
        if ((l & 15) == 0) {
            int rbase = mw * 64 + m * 16 + (l >> 4) * 4;
#pragma unroll
            for (int ri = 0; ri < 4; ++ri)
                Osum[nwv * 256 + rbase + ri] = po[ri];
        }
    }
    __syncthreads();
    if (tid < 256) {
        int v = v0 + tid;
        if (v < N_VOX) out[v] = Osum[tid] + Osum[256 + tid] + b4[0];
    }
}

// ---------------------------------------------------------------------------
extern "C" void kernel_launch(void* const* d_in, const int* in_sizes, int n_in,
                              void* d_out, int out_size, void* d_ws,
                              size_t ws_size, hipStream_t stream) {
    const float* feat = (const float*)d_in[0];
    const int* t      = (const int*)d_in[1];
    const int* nidx   = (const int*)d_in[2];
    const float* W1   = (const float*)d_in[3];
    const float* b1   = (const float*)d_in[4];
    const float* W2   = (const float*)d_in[5];
    const float* b2   = (const float*)d_in[6];
    const float* W3   = (const float*)d_in[7];
    const float* b3   = (const float*)d_in[8];
    const float* W4   = (const float*)d_in[9];
    const float* b4   = (const float*)d_in[10];
    float* out = (float*)d_out;

    char* ws = (char*)d_ws;
    size_t off = 0;
    unsigned short* xeb = (unsigned short*)(ws + off);
    off += ((size_t)(N_VOX + 1) * 8 * 2 + 255) & ~(size_t)255;
    unsigned short* h1b = (unsigned short*)(ws + off);
    off += ((size_t)(N_VOX + 1) * CCH * 2 + 255) & ~(size_t)255;
    unsigned short* W1f = (unsigned short*)(ws + off);
    off += ((size_t)7 * 8 * 64 * 8 * 2 + 255) & ~(size_t)255;
    unsigned short* W2f = (unsigned short*)(ws + off);
    off += ((size_t)(KOFF + 1) * 4 * 8 * 64 * 8 * 2 + 255) & ~(size_t)255;
    unsigned short* W3f = (unsigned short*)(ws + off);

    int grid1 = (N_VOX + 127) / 128;
    int grid2 = (N_VOX + 255) / 256;
    embed_kernel<<<(N_VOX + 1 + 255) / 256, 256, 0, stream>>>(feat, t, xeb);
    convert_w1<<<(7 * 8 * 64 + 255) / 256, 256, 0, stream>>>(W1, W1f);
    convert_w2<<<(KOFF * 4 * 8 * 64) / 256, 256, 0, stream>>>(W2, W2f);
    convert_w3<<<(4 * 8 * 64 + 255) / 256, 256, 0, stream>>>(W3, W3f);
    conv1_mfma<<<grid1, 256, 0, stream>>>(xeb, nidx, W1f, b1, h1b);
    conv2_mfma<<<grid2, 512, 0, stream>>>(h1b, nidx, W2f, b2, W3f, b3, W4, b4, out);
}

// Round 16
// 278.206 us; speedup vs baseline: 2.1340x; 1.5052x over previous
//
#include <hip/hip_runtime.h>
#include <math.h>

#define N_VOX 200000
#define CCH   128
#define KOFF  27

typedef __attribute__((ext_vector_type(8))) short bf16x8;
typedef __attribute__((ext_vector_type(4))) float f32x4;

__device__ __forceinline__ float silu_f(float x) {
    return x / (1.0f + expf(-x));
}
__device__ __forceinline__ unsigned short f2bf(float x) {
    unsigned int u = __float_as_uint(x);
    u = (u + 0x7FFFu + ((u >> 16) & 1u)) >> 16;
    return (unsigned short)u;
}
// bijective XCD-aware block swizzle (m204 variant)
__device__ __forceinline__ int xcd_swz(int orig, int nwg) {
    int q = nwg >> 3, r = nwg & 7;
    int xcd = orig & 7, pos = orig >> 3;
    return (xcd < r ? xcd * (q + 1) : r * (q + 1) + (xcd - r) * q) + pos;
}
// async 16B global -> LDS (direct-to-shared DMA)
__device__ __forceinline__ void gload_lds16(const void* g, void* l) {
    __builtin_amdgcn_global_load_lds(
        (const __attribute__((address_space(1))) unsigned int*)g,
        (__attribute__((address_space(3))) unsigned int*)l, 16, 0, 0);
}

// ---------------------------------------------------------------------------
// Kernel 1: time embedding -> bf16 xeb[(N+1)][8] = {feat, sin*3, cos*3, 0}
// ---------------------------------------------------------------------------
__global__ void embed_kernel(const float* __restrict__ feat,
                             const int* __restrict__ t,
                             unsigned short* __restrict__ xeb) {
    int i = blockIdx.x * blockDim.x + threadIdx.x;
    if (i > N_VOX) return;
    union { unsigned short u[8]; int4 v; } o;
    if (i == N_VOX) {
        o.v = make_int4(0, 0, 0, 0);
    } else {
        o.u[0] = f2bf(feat[i]);
        float tf = (float)t[i];
#pragma unroll
        for (int kk = 0; kk < 3; ++kk) {
            float freq = (float)M_PI * (float)(1 << kk);
            float ang = tf * freq;
            o.u[1 + kk] = f2bf(sinf(ang));
            o.u[4 + kk] = f2bf(cosf(ang));
        }
        o.u[7] = 0;
    }
    *(int4*)(xeb + (size_t)i * 8) = o.v;
}

// ---------------------------------------------------------------------------
// Weight repacks to MFMA-fragment-linear bf16 (B-operand layout).
// ---------------------------------------------------------------------------
__global__ void convert_w1(const float* __restrict__ W1,
                           unsigned short* __restrict__ W1f) {
    int g = blockIdx.x * 256 + threadIdx.x;
    if (g >= 7 * 8 * 64) return;
    int l = g & 63;
    int rest = g >> 6;
    int nf = rest & 7;
    int kk = rest >> 3;
    int o = kk * 4 + (l >> 4);
    int co = nf * 16 + (l & 15);
    union { unsigned short u[8]; int4 v; } out;
#pragma unroll
    for (int j = 0; j < 8; ++j) {
        float w = 0.f;
        if (o < KOFF && j < 7) w = W1[((size_t)o * 7 + j) * CCH + co];
        out.u[j] = f2bf(w);
    }
    *(int4*)(W1f + (size_t)g * 8) = out.v;
}

__global__ void convert_w2(const float* __restrict__ W2,
                           unsigned short* __restrict__ W2f) {
    int g = blockIdx.x * 256 + threadIdx.x;
    int l = g & 63;
    int rest = g >> 6;
    int nf = rest & 7;
    int kkk = rest >> 3;
    int k = kkk >> 2, kk = kkk & 3;
    int ci0 = kk * 32 + (l >> 4) * 8;
    int co = nf * 16 + (l & 15);
    union { unsigned short u[8]; int4 v; } out;
#pragma unroll
    for (int j = 0; j < 8; ++j)
        out.u[j] = f2bf(W2[((size_t)k * CCH + ci0 + j) * CCH + co]);
    *(int4*)(W2f + (size_t)g * 8) = out.v;
}

__global__ void convert_w3(const float* __restrict__ W3,
                           unsigned short* __restrict__ W3f) {
    int g = blockIdx.x * 256 + threadIdx.x;
    if (g >= 4 * 8 * 64) return;
    int l = g & 63;
    int rest = g >> 6;
    int nf = rest & 7;
    int kk = rest >> 3;
    int ci0 = kk * 32 + (l >> 4) * 8;
    int co = nf * 16 + (l & 15);
    union { unsigned short u[8]; int4 v; } out;
#pragma unroll
    for (int j = 0; j < 8; ++j)
        out.u[j] = f2bf(W3[(size_t)(ci0 + j) * CCH + co]);
    *(int4*)(W3f + (size_t)g * 8) = out.v;
}

// ---------------------------------------------------------------------------
// Kernel 2: conv1 via MFMA. 128 vox x 128 ch per block, K = 7 steps of 32.
// ---------------------------------------------------------------------------
__global__ __launch_bounds__(256) void conv1_mfma(
    const unsigned short* __restrict__ xeb, const int* __restrict__ nidx,
    const unsigned short* __restrict__ W1f, const float* __restrict__ b1,
    unsigned short* __restrict__ h1b) {
    __shared__ int4 bufmem[2048];
    __shared__ int idxAll[128 * 28];

    int tid = threadIdx.x;
    int l = tid & 63, w = tid >> 6;
    int mw = w >> 1, nwv = w & 1;
    int wg = xcd_swz(blockIdx.x, gridDim.x);
    int v0 = wg * 128;

    for (int g = tid; g < KOFF * 128; g += 256) {
        int k = g >> 7, vi = g & 127;
        int v = v0 + vi;
        idxAll[vi * 28 + k] = (v < N_VOX) ? nidx[(size_t)k * N_VOX + v] : N_VOX;
    }
    if (tid < 128) idxAll[tid * 28 + 27] = N_VOX;
    __syncthreads();

    f32x4 acc[4][4];
#pragma unroll
    for (int m = 0; m < 4; ++m)
#pragma unroll
        for (int n = 0; n < 4; ++n) acc[m][n] = (f32x4)0.f;

    {
        int4 g0[2]; int rr[2], cc[2];
#pragma unroll
        for (int u = 0; u < 2; ++u) {
            int q = u * 256 + tid;
            int r = q >> 2, oo = q & 3;
            int idx = idxAll[r * 28 + oo];
            g0[u] = *(const int4*)(xeb + (size_t)idx * 8);
            rr[u] = r; cc[u] = oo ^ (r & 3);
        }
#pragma unroll
        for (int u = 0; u < 2; ++u) bufmem[rr[u] * 5 + cc[u]] = g0[u];
    }
    __syncthreads();

    for (int kk = 0; kk < 7; ++kk) {
        int cur = kk & 1;
        int4 gg[2]; int rr[2], cc[2];
        if (kk < 6) {
#pragma unroll
            for (int u = 0; u < 2; ++u) {
                int q = u * 256 + tid;
                int r = q >> 2, oo = q & 3;
                int idx = idxAll[r * 28 + (kk + 1) * 4 + oo];
                gg[u] = *(const int4*)(xeb + (size_t)idx * 8);
                rr[u] = r; cc[u] = oo ^ (r & 3);
            }
        }
        bf16x8 a[4], b[4];
#pragma unroll
        for (int n = 0; n < 4; ++n) {
            int nf = nwv * 4 + n;
            b[n] = *(const bf16x8*)(W1f + ((size_t)(kk * 8 + nf) * 64 + l) * 8);
        }
#pragma unroll
        for (int m = 0; m < 4; ++m) {
            int r = mw * 64 + m * 16 + (l & 15);
            int c = l >> 4;
            a[m] = *(const bf16x8*)&bufmem[cur * 640 + r * 5 + (c ^ (r & 3))];
        }
#pragma unroll
        for (int m = 0; m < 4; ++m)
#pragma unroll
            for (int n = 0; n < 4; ++n)
                acc[m][n] = __builtin_amdgcn_mfma_f32_16x16x32_bf16(
                    a[m], b[n], acc[m][n], 0, 0, 0);
        if (kk < 6) {
#pragma unroll
            for (int u = 0; u < 2; ++u)
                bufmem[(cur ^ 1) * 640 + rr[u] * 5 + cc[u]] = gg[u];
        }
        __syncthreads();
    }

    float bias[4];
#pragma unroll
    for (int n = 0; n < 4; ++n) bias[n] = b1[nwv * 64 + n * 16 + (l & 15)];
    unsigned short* H16 = (unsigned short*)bufmem;
#pragma unroll
    for (int m = 0; m < 4; ++m) {
        int rbase = mw * 64 + m * 16 + (l >> 4) * 4;
#pragma unroll
        for (int n = 0; n < 4; ++n) {
            int ch = nwv * 64 + n * 16 + (l & 15);
            int c = ch >> 3;
            f32x4 d = acc[m][n];
#pragma unroll
            for (int ri = 0; ri < 4; ++ri) {
                int r = rbase + ri;
                int s = (c & 8) | ((c & 7) ^ (r & 7));
                H16[r * 128 + s * 8 + (ch & 7)] = f2bf(silu_f(d[ri] + bias[n]));
            }
        }
    }
    __syncthreads();
#pragma unroll
    for (int u = 0; u < 8; ++u) {
        int q = u * 256 + tid;
        int r = q >> 4, s = q & 15;
        int c = (s & 8) | ((s & 7) ^ (r & 7));
        int v = v0 + r;
        if (v < N_VOX)
            *(int4*)(h1b + (size_t)v * CCH + c * 8) = bufmem[r * 16 + s];
    }
    if (blockIdx.x == 0 && tid < 16)
        *(int4*)(h1b + (size_t)N_VOX * CCH + tid * 8) = make_int4(0, 0, 0, 0);
}

// ---------------------------------------------------------------------------
// Kernel 3: conv2 = r12 (best known: BM=256, 256 thr, 4 waves, acc[8][4],
// BK=64 dbuf frag-tiled LDS, T3-min schedule) + ONE fix: the per-2-steps
// idx refresh is now {global load FIRST in the step} ... {ds_write AFTER the
// MFMAs}. In r12 the inline load+ds_write forced an in-order vmcnt drain of
// the 8 staging gloads BEFORE the MFMAs on every even step. Now the idx
// load is the oldest outstanding op (its ds_write waits at vmcnt(16) ->
// free after the B-wait at vmcnt(8)); staged gathers stay in flight under
// the full MFMA phase on every step.
// ---------------------------------------------------------------------------
#define STAGE_S(buf, sq, ib) {                                             \
    _Pragma("unroll") for (int _u = 0; _u < 8; ++_u) {                     \
        int _q = _u * 256 + tid;                                           \
        int _row = ((_q >> 7) << 4) | (_q & 15);                           \
        int _hi = (_q >> 4) & 3;                                           \
        int _kk = (_q >> 6) & 1;                                           \
        int _idx = idxbuf[ib][_row];                                       \
        gload_lds16((const char*)h1b + ((size_t)(unsigned)_idx << 8) +     \
                        ((sq) & 1) * 128 + _kk * 64 + _hi * 16,            \
                    (void*)&Abuf[buf][_q]);                                \
    }                                                                      \
}

#define LOADB_S(dst, sq) {                                                 \
    const unsigned short* _wb = W2f + (size_t)((sq) >> 1) * 16384 +        \
                                (size_t)((sq) & 1) * 2 * 4096;             \
    _Pragma("unroll") for (int _kk = 0; _kk < 2; ++_kk)                    \
        _Pragma("unroll") for (int _n = 0; _n < 4; ++_n)                   \
            dst[_kk][_n] = *(const bf16x8*)(_wb +                          \
                ((size_t)(_kk * 8 + nwv * 4 + _n) * 64 + l) * 8);          \
}

#define MFMA_S(cur, bfr) {                                                 \
    _Pragma("unroll") for (int _kk = 0; _kk < 2; ++_kk) {                  \
        bf16x8 _a[8];                                                      \
        _Pragma("unroll") for (int _m = 0; _m < 8; ++_m) {                 \
            int _R = mw * 8 + _m;                                          \
            _a[_m] = *(const bf16x8*)&Abuf[cur][((_R * 2 + _kk) << 6) + l];\
        }                                                                  \
        __builtin_amdgcn_s_setprio(1);                                     \
        _Pragma("unroll") for (int _m = 0; _m < 8; ++_m)                   \
            _Pragma("unroll") for (int _n = 0; _n < 4; ++_n)               \
                acc[_m][_n] = __builtin_amdgcn_mfma_f32_16x16x32_bf16(     \
                    _a[_m], bfr[_kk][_n], acc[_m][_n], 0, 0, 0);           \
        __builtin_amdgcn_s_setprio(0);                                     \
    }                                                                      \
}

#define STEP_S(SQ, CUR, DO_STAGE, DO_IDX) {                                \
    int _idxreg = N_VOX;                                                   \
    if (DO_IDX) {                                                          \
        int _k1 = ((SQ) >> 1) + 1;                                         \
        int _v = v0 + tid;                                                 \
        _idxreg = (_v < N_VOX) ? nidx[(size_t)_k1 * N_VOX + _v] : N_VOX;   \
    }                                                                      \
    __builtin_amdgcn_sched_barrier(0);                                     \
    bf16x8 bfr[2][4];                                                      \
    LOADB_S(bfr, SQ);                                                      \
    __builtin_amdgcn_sched_barrier(0);                                     \
    if (DO_STAGE) { STAGE_S((CUR) ^ 1, (SQ) + 1, ((((SQ) + 1) >> 1) & 1)); }\
    __builtin_amdgcn_sched_barrier(0);                                     \
    MFMA_S(CUR, bfr);                                                      \
    if (DO_IDX) {                                                          \
        int _k1 = ((SQ) >> 1) + 1;                                         \
        idxbuf[_k1 & 1][tid] = _idxreg;                                    \
        asm volatile("s_waitcnt lgkmcnt(0)" ::: "memory");                 \
    }                                                                      \
    asm volatile("s_waitcnt vmcnt(0)" ::: "memory");                       \
    __builtin_amdgcn_s_barrier();                                          \
}

__global__ __launch_bounds__(256, 2) void conv2_mfma(
    const unsigned short* __restrict__ h1b, const int* __restrict__ nidx,
    const unsigned short* __restrict__ W2f, const float* __restrict__ b2,
    const unsigned short* __restrict__ W3f, const float* __restrict__ b3,
    const float* __restrict__ W4, const float* __restrict__ b4,
    float* __restrict__ out) {
    __shared__ int4 Abuf[2][2048];   // 64 KB, frag-tiled BK=64 A-tiles
    __shared__ int idxbuf[2][256];   // 2 KB, per-k gather indices
    __shared__ float Osum[512];      // 2 KB tail reduce

    int tid = threadIdx.x;
    int l = tid & 63, w = tid >> 6;
    int mw = w >> 1, nwv = w & 1;
    int wg = xcd_swz(blockIdx.x, gridDim.x);
    int v0 = wg * 256;

    f32x4 acc[8][4];
#pragma unroll
    for (int m = 0; m < 8; ++m)
#pragma unroll
        for (int n = 0; n < 4; ++n) acc[m][n] = (f32x4)0.f;

    // prologue: idx(k=0) -> sync -> stage step0 + idx(k=1) -> drain -> sync
    {
        int v = v0 + tid;
        idxbuf[0][tid] = (v < N_VOX) ? nidx[v] : N_VOX;
    }
    __syncthreads();
    STAGE_S(0, 0, 0);
    {
        int v = v0 + tid;
        idxbuf[1][tid] = (v < N_VOX) ? nidx[(size_t)N_VOX + v] : N_VOX;
    }
    asm volatile("s_waitcnt vmcnt(0)" ::: "memory");
    __syncthreads();

    for (int sp = 0; sp < 52; sp += 2) {
        STEP_S(sp, 0, true, ((sp >> 1) + 1 < KOFF));
        STEP_S(sp + 1, 1, true, false);
    }
    STEP_S(52, 0, true, false);    // stages step 53
    STEP_S(53, 1, false, false);   // last: no staging

    // ---- fused tail: H = bf16(silu(acc+b2)) -> LDS; P = H @ W3; out ----
    float bias2[4];
#pragma unroll
    for (int n = 0; n < 4; ++n) bias2[n] = b2[nwv * 64 + n * 16 + (l & 15)];
    unsigned short* H16 = (unsigned short*)&Abuf[0][0];   // 256x128 = 64 KB
#pragma unroll
    for (int m = 0; m < 8; ++m) {
        int rbase = mw * 128 + m * 16 + (l >> 4) * 4;
#pragma unroll
        for (int n = 0; n < 4; ++n) {
            int ch = nwv * 64 + n * 16 + (l & 15);
            int c = ch >> 3;
            f32x4 d = acc[m][n];
#pragma unroll
            for (int ri = 0; ri < 4; ++ri) {
                int r = rbase + ri;
                int s = (c & 8) | ((c & 7) ^ (r & 7));
                H16[r * 128 + s * 8 + (ch & 7)] = f2bf(silu_f(d[ri] + bias2[n]));
            }
        }
    }
    __syncthreads();

    f32x4 p[8][4];
#pragma unroll
    for (int m = 0; m < 8; ++m)
#pragma unroll
        for (int n = 0; n < 4; ++n) p[m][n] = (f32x4)0.f;
#pragma unroll
    for (int kk = 0; kk < 4; ++kk) {
        bf16x8 a[8], b[4];
#pragma unroll
        for (int n = 0; n < 4; ++n) {
            int nf = nwv * 4 + n;
            b[n] = *(const bf16x8*)(W3f + ((size_t)(kk * 8 + nf) * 64 + l) * 8);
        }
#pragma unroll
        for (int m = 0; m < 8; ++m) {
            int r = mw * 128 + m * 16 + (l & 15);
            int c = kk * 4 + (l >> 4);
            int s = (c & 8) | ((c & 7) ^ (r & 7));
            a[m] = *(const bf16x8*)&H16[r * 128 + s * 8];
        }
#pragma unroll
        for (int m = 0; m < 8; ++m)
#pragma unroll
            for (int n = 0; n < 4; ++n)
                p[m][n] = __builtin_amdgcn_mfma_f32_16x16x32_bf16(
                    a[m], b[n], p[m][n], 0, 0, 0);
    }

    float w4v[4], b3v[4];
#pragma unroll
    for (int n = 0; n < 4; ++n) {
        int ch = nwv * 64 + n * 16 + (l & 15);
        w4v[n] = W4[ch];
        b3v[n] = b3[ch];
    }
#pragma unroll
    for (int m = 0; m < 8; ++m) {
        float po[4] = {0.f, 0.f, 0.f, 0.f};
#pragma unroll
        for (int n = 0; n < 4; ++n) {
            f32x4 d = p[m][n];
#pragma unroll
            for (int ri = 0; ri < 4; ++ri)
                po[ri] += silu_f(d[ri] + b3v[n]) * w4v[n];
        }
#pragma unroll
        for (int off = 1; off < 16; off <<= 1)
#pragma unroll
            for (int ri = 0; ri < 4; ++ri)
                po[ri] += __shfl_xor(po[ri], off, 64);
        if ((l & 15) == 0) {
            int rbase = mw * 128 + m * 16 + (l >> 4) * 4;
#pragma unroll
            for (int ri = 0; ri < 4; ++ri)
                Osum[nwv * 256 + rbase + ri] = po[ri];
        }
    }
    __syncthreads();
    {
        int v = v0 + tid;
        if (v < N_VOX) out[v] = Osum[tid] + Osum[256 + tid] + b4[0];
    }
}

// ---------------------------------------------------------------------------
extern "C" void kernel_launch(void* const* d_in, const int* in_sizes, int n_in,
                              void* d_out, int out_size, void* d_ws,
                              size_t ws_size, hipStream_t stream) {
    const float* feat = (const float*)d_in[0];
    const int* t      = (const int*)d_in[1];
    const int* nidx   = (const int*)d_in[2];
    const float* W1   = (const float*)d_in[3];
    const float* b1   = (const float*)d_in[4];
    const float* W2   = (const float*)d_in[5];
    const float* b2   = (const float*)d_in[6];
    const float* W3   = (const float*)d_in[7];
    const float* b3   = (const float*)d_in[8];
    const float* W4   = (const float*)d_in[9];
    const float* b4   = (const float*)d_in[10];
    float* out = (float*)d_out;

    char* ws = (char*)d_ws;
    size_t off = 0;
    unsigned short* xeb = (unsigned short*)(ws + off);
    off += ((size_t)(N_VOX + 1) * 8 * 2 + 255) & ~(size_t)255;
    unsigned short* h1b = (unsigned short*)(ws + off);
    off += ((size_t)(N_VOX + 1) * CCH * 2 + 255) & ~(size_t)255;
    unsigned short* W1f = (unsigned short*)(ws + off);
    off += ((size_t)7 * 8 * 64 * 8 * 2 + 255) & ~(size_t)255;
    unsigned short* W2f = (unsigned short*)(ws + off);
    off += ((size_t)(KOFF + 1) * 4 * 8 * 64 * 8 * 2 + 255) & ~(size_t)255;
    unsigned short* W3f = (unsigned short*)(ws + off);

    int grid1 = (N_VOX + 127) / 128;
    int grid2 = (N_VOX + 255) / 256;
    embed_kernel<<<(N_VOX + 1 + 255) / 256, 256, 0, stream>>>(feat, t, xeb);
    convert_w1<<<(7 * 8 * 64 + 255) / 256, 256, 0, stream>>>(W1, W1f);
    convert_w2<<<(KOFF * 4 * 8 * 64) / 256, 256, 0, stream>>>(W2, W2f);
    convert_w3<<<(4 * 8 * 64 + 255) / 256, 256, 0, stream>>>(W3, W3f);
    conv1_mfma<<<grid1, 256, 0, stream>>>(xeb, nidx, W1f, b1, h1b);
    conv2_mfma<<<grid2, 256, 0, stream>>>(h1b, nidx, W2f, b2, W3f, b3, W4, b4, out);
}

// Round 17
// 261.446 us; speedup vs baseline: 2.2708x; 1.0641x over previous
//
#include <hip/hip_runtime.h>
#include <math.h>

#define N_VOX 200000
#define CCH   128
#define KOFF  27
#define BM2   224            // conv2 voxel tile (893 blocks -> 87% grid eff)
#define NRU   14             // row units of 16 (BM2/16)

typedef __attribute__((ext_vector_type(8))) short bf16x8;
typedef __attribute__((ext_vector_type(4))) float f32x4;

__device__ __forceinline__ float silu_f(float x) {
    return x / (1.0f + expf(-x));
}
__device__ __forceinline__ unsigned short f2bf(float x) {
    unsigned int u = __float_as_uint(x);
    u = (u + 0x7FFFu + ((u >> 16) & 1u)) >> 16;
    return (unsigned short)u;
}
// bijective XCD-aware block swizzle (m204 variant)
__device__ __forceinline__ int xcd_swz(int orig, int nwg) {
    int q = nwg >> 3, r = nwg & 7;
    int xcd = orig & 7, pos = orig >> 3;
    return (xcd < r ? xcd * (q + 1) : r * (q + 1) + (xcd - r) * q) + pos;
}
// async 16B global -> LDS (direct-to-shared DMA)
__device__ __forceinline__ void gload_lds16(const void* g, void* l) {
    __builtin_amdgcn_global_load_lds(
        (const __attribute__((address_space(1))) unsigned int*)g,
        (__attribute__((address_space(3))) unsigned int*)l, 16, 0, 0);
}

// ---------------------------------------------------------------------------
// Kernel 1: time embedding -> bf16 xeb[(N+1)][8] = {feat, sin*3, cos*3, 0}
// ---------------------------------------------------------------------------
__global__ void embed_kernel(const float* __restrict__ feat,
                             const int* __restrict__ t,
                             unsigned short* __restrict__ xeb) {
    int i = blockIdx.x * blockDim.x + threadIdx.x;
    if (i > N_VOX) return;
    union { unsigned short u[8]; int4 v; } o;
    if (i == N_VOX) {
        o.v = make_int4(0, 0, 0, 0);
    } else {
        o.u[0] = f2bf(feat[i]);
        float tf = (float)t[i];
#pragma unroll
        for (int kk = 0; kk < 3; ++kk) {
            float freq = (float)M_PI * (float)(1 << kk);
            float ang = tf * freq;
            o.u[1 + kk] = f2bf(sinf(ang));
            o.u[4 + kk] = f2bf(cosf(ang));
        }
        o.u[7] = 0;
    }
    *(int4*)(xeb + (size_t)i * 8) = o.v;
}

// ---------------------------------------------------------------------------
// Weight repacks to MFMA-fragment-linear bf16 (B-operand layout).
// ---------------------------------------------------------------------------
__global__ void convert_w1(const float* __restrict__ W1,
                           unsigned short* __restrict__ W1f) {
    int g = blockIdx.x * 256 + threadIdx.x;
    if (g >= 7 * 8 * 64) return;
    int l = g & 63;
    int rest = g >> 6;
    int nf = rest & 7;
    int kk = rest >> 3;
    int o = kk * 4 + (l >> 4);
    int co = nf * 16 + (l & 15);
    union { unsigned short u[8]; int4 v; } out;
#pragma unroll
    for (int j = 0; j < 8; ++j) {
        float w = 0.f;
        if (o < KOFF && j < 7) w = W1[((size_t)o * 7 + j) * CCH + co];
        out.u[j] = f2bf(w);
    }
    *(int4*)(W1f + (size_t)g * 8) = out.v;
}

__global__ void convert_w2(const float* __restrict__ W2,
                           unsigned short* __restrict__ W2f) {
    int g = blockIdx.x * 256 + threadIdx.x;
    int l = g & 63;
    int rest = g >> 6;
    int nf = rest & 7;
    int kkk = rest >> 3;
    int k = kkk >> 2, kk = kkk & 3;
    int ci0 = kk * 32 + (l >> 4) * 8;
    int co = nf * 16 + (l & 15);
    union { unsigned short u[8]; int4 v; } out;
#pragma unroll
    for (int j = 0; j < 8; ++j)
        out.u[j] = f2bf(W2[((size_t)k * CCH + ci0 + j) * CCH + co]);
    *(int4*)(W2f + (size_t)g * 8) = out.v;
}

__global__ void convert_w3(const float* __restrict__ W3,
                           unsigned short* __restrict__ W3f) {
    int g = blockIdx.x * 256 + threadIdx.x;
    if (g >= 4 * 8 * 64) return;
    int l = g & 63;
    int rest = g >> 6;
    int nf = rest & 7;
    int kk = rest >> 3;
    int ci0 = kk * 32 + (l >> 4) * 8;
    int co = nf * 16 + (l & 15);
    union { unsigned short u[8]; int4 v; } out;
#pragma unroll
    for (int j = 0; j < 8; ++j)
        out.u[j] = f2bf(W3[(size_t)(ci0 + j) * CCH + co]);
    *(int4*)(W3f + (size_t)g * 8) = out.v;
}

// ---------------------------------------------------------------------------
// Kernel 2: conv1 via MFMA. 128 vox x 128 ch per block, K = 7 steps of 32.
// ---------------------------------------------------------------------------
__global__ __launch_bounds__(256) void conv1_mfma(
    const unsigned short* __restrict__ xeb, const int* __restrict__ nidx,
    const unsigned short* __restrict__ W1f, const float* __restrict__ b1,
    unsigned short* __restrict__ h1b) {
    __shared__ int4 bufmem[2048];
    __shared__ int idxAll[128 * 28];

    int tid = threadIdx.x;
    int l = tid & 63, w = tid >> 6;
    int mw = w >> 1, nwv = w & 1;
    int wg = xcd_swz(blockIdx.x, gridDim.x);
    int v0 = wg * 128;

    for (int g = tid; g < KOFF * 128; g += 256) {
        int k = g >> 7, vi = g & 127;
        int v = v0 + vi;
        idxAll[vi * 28 + k] = (v < N_VOX) ? nidx[(size_t)k * N_VOX + v] : N_VOX;
    }
    if (tid < 128) idxAll[tid * 28 + 27] = N_VOX;
    __syncthreads();

    f32x4 acc[4][4];
#pragma unroll
    for (int m = 0; m < 4; ++m)
#pragma unroll
        for (int n = 0; n < 4; ++n) acc[m][n] = (f32x4)0.f;

    {
        int4 g0[2]; int rr[2], cc[2];
#pragma unroll
        for (int u = 0; u < 2; ++u) {
            int q = u * 256 + tid;
            int r = q >> 2, oo = q & 3;
            int idx = idxAll[r * 28 + oo];
            g0[u] = *(const int4*)(xeb + (size_t)idx * 8);
            rr[u] = r; cc[u] = oo ^ (r & 3);
        }
#pragma unroll
        for (int u = 0; u < 2; ++u) bufmem[rr[u] * 5 + cc[u]] = g0[u];
    }
    __syncthreads();

    for (int kk = 0; kk < 7; ++kk) {
        int cur = kk & 1;
        int4 gg[2]; int rr[2], cc[2];
        if (kk < 6) {
#pragma unroll
            for (int u = 0; u < 2; ++u) {
                int q = u * 256 + tid;
                int r = q >> 2, oo = q & 3;
                int idx = idxAll[r * 28 + (kk + 1) * 4 + oo];
                gg[u] = *(const int4*)(xeb + (size_t)idx * 8);
                rr[u] = r; cc[u] = oo ^ (r & 3);
            }
        }
        bf16x8 a[4], b[4];
#pragma unroll
        for (int n = 0; n < 4; ++n) {
            int nf = nwv * 4 + n;
            b[n] = *(const bf16x8*)(W1f + ((size_t)(kk * 8 + nf) * 64 + l) * 8);
        }
#pragma unroll
        for (int m = 0; m < 4; ++m) {
            int r = mw * 64 + m * 16 + (l & 15);
            int c = l >> 4;
            a[m] = *(const bf16x8*)&bufmem[cur * 640 + r * 5 + (c ^ (r & 3))];
        }
#pragma unroll
        for (int m = 0; m < 4; ++m)
#pragma unroll
            for (int n = 0; n < 4; ++n)
                acc[m][n] = __builtin_amdgcn_mfma_f32_16x16x32_bf16(
                    a[m], b[n], acc[m][n], 0, 0, 0);
        if (kk < 6) {
#pragma unroll
            for (int u = 0; u < 2; ++u)
                bufmem[(cur ^ 1) * 640 + rr[u] * 5 + cc[u]] = gg[u];
        }
        __syncthreads();
    }

    float bias[4];
#pragma unroll
    for (int n = 0; n < 4; ++n) bias[n] = b1[nwv * 64 + n * 16 + (l & 15)];
    unsigned short* H16 = (unsigned short*)bufmem;
#pragma unroll
    for (int m = 0; m < 4; ++m) {
        int rbase = mw * 64 + m * 16 + (l >> 4) * 4;
#pragma unroll
        for (int n = 0; n < 4; ++n) {
            int ch = nwv * 64 + n * 16 + (l & 15);
            int c = ch >> 3;
            f32x4 d = acc[m][n];
#pragma unroll
            for (int ri = 0; ri < 4; ++ri) {
                int r = rbase + ri;
                int s = (c & 8) | ((c & 7) ^ (r & 7));
                H16[r * 128 + s * 8 + (ch & 7)] = f2bf(silu_f(d[ri] + bias[n]));
            }
        }
    }
    __syncthreads();
#pragma unroll
    for (int u = 0; u < 8; ++u) {
        int q = u * 256 + tid;
        int r = q >> 4, s = q & 15;
        int c = (s & 8) | ((s & 7) ^ (r & 7));
        int v = v0 + r;
        if (v < N_VOX)
            *(int4*)(h1b + (size_t)v * CCH + c * 8) = bufmem[r * 16 + s];
    }
    if (blockIdx.x == 0 && tid < 16)
        *(int4*)(h1b + (size_t)N_VOX * CCH + tid * 8) = make_int4(0, 0, 0, 0);
}

// ---------------------------------------------------------------------------
// Kernel 3: conv2 = r12/r16 structure at BM=224 (7 m-tiles/wave, acc[7][4])
// to fix grid quantization: 893 blocks / 512 slots = 2 rounds with round 2
// 74% full (was 782/512 -> round 2 53% full). Same frag-tiled conflict-free
// LDS, same T3-min schedule, idx-hoist from r16. 56KB dbuf -> 2 blocks/CU.
// ---------------------------------------------------------------------------
#define STAGE_S(buf, sq, ib) {                                             \
    _Pragma("unroll") for (int _u = 0; _u < 7; ++_u) {                     \
        int _q = _u * 256 + tid;                                           \
        int _row = ((_q >> 7) << 4) | (_q & 15);                           \
        int _hi = (_q >> 4) & 3;                                           \
        int _kk = (_q >> 6) & 1;                                           \
        int _idx = idxbuf[ib][_row];                                       \
        gload_lds16((const char*)h1b + ((size_t)(unsigned)_idx << 8) +     \
                        ((sq) & 1) * 128 + _kk * 64 + _hi * 16,            \
                    (void*)&Abuf[buf][_q]);                                \
    }                                                                      \
}

#define LOADB_S(dst, sq) {                                                 \
    const unsigned short* _wb = W2f + (size_t)((sq) >> 1) * 16384 +        \
                                (size_t)((sq) & 1) * 2 * 4096;             \
    _Pragma("unroll") for (int _kk = 0; _kk < 2; ++_kk)                    \
        _Pragma("unroll") for (int _n = 0; _n < 4; ++_n)                   \
            dst[_kk][_n] = *(const bf16x8*)(_wb +                          \
                ((size_t)(_kk * 8 + nwv * 4 + _n) * 64 + l) * 8);          \
}

#define MFMA_S(cur, bfr) {                                                 \
    _Pragma("unroll") for (int _kk = 0; _kk < 2; ++_kk) {                  \
        bf16x8 _a[7];                                                      \
        _Pragma("unroll") for (int _m = 0; _m < 7; ++_m) {                 \
            int _R = mw * 7 + _m;                                          \
            _a[_m] = *(const bf16x8*)&Abuf[cur][((_R * 2 + _kk) << 6) + l];\
        }                                                                  \
        __builtin_amdgcn_s_setprio(1);                                     \
        _Pragma("unroll") for (int _m = 0; _m < 7; ++_m)                   \
            _Pragma("unroll") for (int _n = 0; _n < 4; ++_n)               \
                acc[_m][_n] = __builtin_amdgcn_mfma_f32_16x16x32_bf16(     \
                    _a[_m], bfr[_kk][_n], acc[_m][_n], 0, 0, 0);           \
        __builtin_amdgcn_s_setprio(0);                                     \
    }                                                                      \
}

#define STEP_S(SQ, CUR, DO_STAGE, DO_IDX) {                                \
    int _idxreg = N_VOX;                                                   \
    if (DO_IDX) {                                                          \
        int _k1 = ((SQ) >> 1) + 1;                                         \
        int _v = v0 + tid;                                                 \
        if (tid < BM2)                                                     \
            _idxreg = (_v < N_VOX) ? nidx[(size_t)_k1 * N_VOX + _v] : N_VOX;\
    }                                                                      \
    __builtin_amdgcn_sched_barrier(0);                                     \
    bf16x8 bfr[2][4];                                                      \
    LOADB_S(bfr, SQ);                                                      \
    __builtin_amdgcn_sched_barrier(0);                                     \
    if (DO_STAGE) { STAGE_S((CUR) ^ 1, (SQ) + 1, ((((SQ) + 1) >> 1) & 1)); }\
    __builtin_amdgcn_sched_barrier(0);                                     \
    MFMA_S(CUR, bfr);                                                      \
    if (DO_IDX) {                                                          \
        int _k1 = ((SQ) >> 1) + 1;                                         \
        if (tid < BM2) idxbuf[_k1 & 1][tid] = _idxreg;                     \
        asm volatile("s_waitcnt lgkmcnt(0)" ::: "memory");                 \
    }                                                                      \
    asm volatile("s_waitcnt vmcnt(0)" ::: "memory");                       \
    __builtin_amdgcn_s_barrier();                                          \
}

__global__ __launch_bounds__(256, 2) void conv2_mfma(
    const unsigned short* __restrict__ h1b, const int* __restrict__ nidx,
    const unsigned short* __restrict__ W2f, const float* __restrict__ b2,
    const unsigned short* __restrict__ W3f, const float* __restrict__ b3,
    const float* __restrict__ W4, const float* __restrict__ b4,
    float* __restrict__ out) {
    __shared__ int4 Abuf[2][NRU * 128];   // 56 KB, frag-tiled BK=64 A-tiles
    __shared__ int idxbuf[2][BM2];        // per-k gather indices
    __shared__ float Osum[2 * BM2];       // tail reduce

    int tid = threadIdx.x;
    int l = tid & 63, w = tid >> 6;
    int mw = w >> 1, nwv = w & 1;
    int wg = xcd_swz(blockIdx.x, gridDim.x);
    int v0 = wg * BM2;

    f32x4 acc[7][4];
#pragma unroll
    for (int m = 0; m < 7; ++m)
#pragma unroll
        for (int n = 0; n < 4; ++n) acc[m][n] = (f32x4)0.f;

    // prologue: idx(k=0) -> sync -> stage step0 + idx(k=1) -> drain -> sync
    if (tid < BM2) {
        int v = v0 + tid;
        idxbuf[0][tid] = (v < N_VOX) ? nidx[v] : N_VOX;
    }
    __syncthreads();
    STAGE_S(0, 0, 0);
    if (tid < BM2) {
        int v = v0 + tid;
        idxbuf[1][tid] = (v < N_VOX) ? nidx[(size_t)N_VOX + v] : N_VOX;
    }
    asm volatile("s_waitcnt vmcnt(0)" ::: "memory");
    __syncthreads();

    for (int sp = 0; sp < 52; sp += 2) {
        STEP_S(sp, 0, true, ((sp >> 1) + 1 < KOFF));
        STEP_S(sp + 1, 1, true, false);
    }
    STEP_S(52, 0, true, false);    // stages step 53
    STEP_S(53, 1, false, false);   // last: no staging

    // ---- fused tail: H = bf16(silu(acc+b2)) -> LDS; P = H @ W3; out ----
    float bias2[4];
#pragma unroll
    for (int n = 0; n < 4; ++n) bias2[n] = b2[nwv * 64 + n * 16 + (l & 15)];
    unsigned short* H16 = (unsigned short*)&Abuf[0][0];   // 224x128 = 56 KB
#pragma unroll
    for (int m = 0; m < 7; ++m) {
        int rbase = mw * 112 + m * 16 + (l >> 4) * 4;
#pragma unroll
        for (int n = 0; n < 4; ++n) {
            int ch = nwv * 64 + n * 16 + (l & 15);
            int c = ch >> 3;
            f32x4 d = acc[m][n];
#pragma unroll
            for (int ri = 0; ri < 4; ++ri) {
                int r = rbase + ri;
                int s = (c & 8) | ((c & 7) ^ (r & 7));
                H16[r * 128 + s * 8 + (ch & 7)] = f2bf(silu_f(d[ri] + bias2[n]));
            }
        }
    }
    __syncthreads();

    f32x4 p[7][4];
#pragma unroll
    for (int m = 0; m < 7; ++m)
#pragma unroll
        for (int n = 0; n < 4; ++n) p[m][n] = (f32x4)0.f;
#pragma unroll
    for (int kk = 0; kk < 4; ++kk) {
        bf16x8 a[7], b[4];
#pragma unroll
        for (int n = 0; n < 4; ++n) {
            int nf = nwv * 4 + n;
            b[n] = *(const bf16x8*)(W3f + ((size_t)(kk * 8 + nf) * 64 + l) * 8);
        }
#pragma unroll
        for (int m = 0; m < 7; ++m) {
            int r = mw * 112 + m * 16 + (l & 15);
            int c = kk * 4 + (l >> 4);
            int s = (c & 8) | ((c & 7) ^ (r & 7));
            a[m] = *(const bf16x8*)&H16[r * 128 + s * 8];
        }
#pragma unroll
        for (int m = 0; m < 7; ++m)
#pragma unroll
            for (int n = 0; n < 4; ++n)
                p[m][n] = __builtin_amdgcn_mfma_f32_16x16x32_bf16(
                    a[m], b[n], p[m][n], 0, 0, 0);
    }

    float w4v[4], b3v[4];
#pragma unroll
    for (int n = 0; n < 4; ++n) {
        int ch = nwv * 64 + n * 16 + (l & 15);
        w4v[n] = W4[ch];
        b3v[n] = b3[ch];
    }
#pragma unroll
    for (int m = 0; m < 7; ++m) {
        float po[4] = {0.f, 0.f, 0.f, 0.f};
#pragma unroll
        for (int n = 0; n < 4; ++n) {
            f32x4 d = p[m][n];
#pragma unroll
            for (int ri = 0; ri < 4; ++ri)
                po[ri] += silu_f(d[ri] + b3v[n]) * w4v[n];
        }
#pragma unroll
        for (int off = 1; off < 16; off <<= 1)
#pragma unroll
            for (int ri = 0; ri < 4; ++ri)
                po[ri] += __shfl_xor(po[ri], off, 64);
        if ((l & 15) == 0) {
            int rbase = mw * 112 + m * 16 + (l >> 4) * 4;
#pragma unroll
            for (int ri = 0; ri < 4; ++ri)
                Osum[nwv * BM2 + rbase + ri] = po[ri];
        }
    }
    __syncthreads();
    if (tid < BM2) {
        int v = v0 + tid;
        if (v < N_VOX) out[v] = Osum[tid] + Osum[BM2 + tid] + b4[0];
    }
}

// ---------------------------------------------------------------------------
extern "C" void kernel_launch(void* const* d_in, const int* in_sizes, int n_in,
                              void* d_out, int out_size, void* d_ws,
                              size_t ws_size, hipStream_t stream) {
    const float* feat = (const float*)d_in[0];
    const int* t      = (const int*)d_in[1];
    const int* nidx   = (const int*)d_in[2];
    const float* W1   = (const float*)d_in[3];
    const float* b1   = (const float*)d_in[4];
    const float* W2   = (const float*)d_in[5];
    const float* b2   = (const float*)d_in[6];
    const float* W3   = (const float*)d_in[7];
    const float* b3   = (const float*)d_in[8];
    const float* W4   = (const float*)d_in[9];
    const float* b4   = (const float*)d_in[10];
    float* out = (float*)d_out;

    char* ws = (char*)d_ws;
    size_t off = 0;
    unsigned short* xeb = (unsigned short*)(ws + off);
    off += ((size_t)(N_VOX + 1) * 8 * 2 + 255) & ~(size_t)255;
    unsigned short* h1b = (unsigned short*)(ws + off);
    off += ((size_t)(N_VOX + 1) * CCH * 2 + 255) & ~(size_t)255;
    unsigned short* W1f = (unsigned short*)(ws + off);
    off += ((size_t)7 * 8 * 64 * 8 * 2 + 255) & ~(size_t)255;
    unsigned short* W2f = (unsigned short*)(ws + off);
    off += ((size_t)(KOFF + 1) * 4 * 8 * 64 * 8 * 2 + 255) & ~(size_t)255;
    unsigned short* W3f = (unsigned short*)(ws + off);

    int grid1 = (N_VOX + 127) / 128;
    int grid2 = (N_VOX + BM2 - 1) / BM2;
    embed_kernel<<<(N_VOX + 1 + 255) / 256, 256, 0, stream>>>(feat, t, xeb);
    convert_w1<<<(7 * 8 * 64 + 255) / 256, 256, 0, stream>>>(W1, W1f);
    convert_w2<<<(KOFF * 4 * 8 * 64) / 256, 256, 0, stream>>>(W2, W2f);
    convert_w3<<<(4 * 8 * 64 + 255) / 256, 256, 0, stream>>>(W3, W3f);
    conv1_mfma<<<grid1, 256, 0, stream>>>(xeb, nidx, W1f, b1, h1b);
    conv2_mfma<<<grid2, 256, 0, stream>>>(h1b, nidx, W2f, b2, W3f, b3, W4, b4, out);
}